// Round 10
// baseline (197.079 us; speedup 1.0000x reference)
//
#include <hip/hip_runtime.h>
#include <hip/hip_bf16.h>

#define RS 0.9999950000374998f  // 1/sqrt(1+1e-5)

__device__ __forceinline__ float eluf(float x) {
    return x > 0.0f ? x : __expf(x) - 1.0f;
}

typedef __attribute__((ext_vector_type(8))) __bf16 bf16x8;
typedef __attribute__((ext_vector_type(4))) float f32x4;
typedef __attribute__((ext_vector_type(4))) unsigned int u32x4;

// ---------------------------------------------------------------------------
// f32-input tiled GEMM (fts_l). OUTB=1 -> bf16 output.
// ---------------------------------------------------------------------------
template <int ACT, int BN, int OUTB>
__global__ __launch_bounds__(256) void gemm_bias_act(
    const float* __restrict__ A, const float* __restrict__ W,
    const float* __restrict__ bias, const float* __restrict__ gamma,
    const float* __restrict__ beta, void* __restrict__ outp,
    int Kdim, int Ncols) {
    __shared__ float As[16][64];
    __shared__ float Bs[16][64];
    const int tid = threadIdx.x;
    const int tx = tid & 15, ty = tid >> 4;
    const long row0 = (long)blockIdx.x * 64;
    const int col0 = blockIdx.y * 64;
    const int rA = tid >> 2, kqA = (tid & 3) << 2;
    const int kkB = tid >> 4, cqB = (tid & 15) << 2;
    float acc[4][4] = {};
    for (int k0 = 0; k0 < Kdim; k0 += 16) {
        const float4 av = *reinterpret_cast<const float4*>(
            A + (row0 + rA) * (long)Kdim + (k0 + kqA));
        const float4 bv = *reinterpret_cast<const float4*>(
            W + (long)(k0 + kkB) * Ncols + (col0 + cqB));
        As[kqA + 0][rA] = av.x;
        As[kqA + 1][rA] = av.y;
        As[kqA + 2][rA] = av.z;
        As[kqA + 3][rA] = av.w;
        *reinterpret_cast<float4*>(&Bs[kkB][cqB]) = bv;
        __syncthreads();
#pragma unroll
        for (int kk = 0; kk < 16; ++kk) {
            float a[4], b[4];
#pragma unroll
            for (int i = 0; i < 4; ++i) a[i] = As[kk][ty * 4 + i];
#pragma unroll
            for (int j = 0; j < 4; ++j) b[j] = Bs[kk][tx * 4 + j];
#pragma unroll
            for (int i = 0; i < 4; ++i)
#pragma unroll
                for (int j = 0; j < 4; ++j) acc[i][j] = fmaf(a[i], b[j], acc[i][j]);
        }
        __syncthreads();
    }
#pragma unroll
    for (int j = 0; j < 4; ++j) {
        const int col = col0 + tx * 4 + j;
        const float bb = bias[col];
        const float gs = BN ? gamma[col] * RS : 0.0f;
        const float bt = BN ? beta[col] : 0.0f;
#pragma unroll
        for (int i = 0; i < 4; ++i) {
            const long row = row0 + ty * 4 + i;
            float v = acc[i][j] + bb;
            if (ACT) v = eluf(v);
            if (BN) v = v * gs + bt;
            if (OUTB)
                reinterpret_cast<__hip_bfloat16*>(outp)[row * Ncols + col] =
                    __float2bfloat16(v);
            else
                reinterpret_cast<float*>(outp)[row * Ncols + col] = v;
        }
    }
}

// ---------------------------------------------------------------------------
// Weight conversion to bf16-transposed forms. One-shot, tiny.
// ---------------------------------------------------------------------------
__global__ __launch_bounds__(256) void convert_weights(
    const float* __restrict__ d1W, const float* __restrict__ d2W,
    const float* __restrict__ pwW, const float* __restrict__ d2Ws,
    __hip_bfloat16* __restrict__ d1Wt, __hip_bfloat16* __restrict__ d2Wt,
    __hip_bfloat16* __restrict__ pwWt, __hip_bfloat16* __restrict__ d2pWt) {
    const int t = blockIdx.x * 256 + threadIdx.x;
    if (t < 65536) {
        const int k = t >> 8, n = t & 255;
        d1Wt[n * 256 + k] = __float2bfloat16(d1W[t]);
        d2Wt[n * 256 + k] = __float2bfloat16(d2W[t]);
    }
    if (t < 24576) {
        const int k = t >> 7, n = t & 127;
        pwWt[n * 192 + k] = __float2bfloat16(pwW[t]);
    }
    if (t < 1024) {
        const int q = t >> 5, c = t & 31;
        d2pWt[c * 32 + q] = __float2bfloat16(d2Ws[t]);
    }
}

// ---------------------------------------------------------------------------
// bf16 MFMA GEMM (R7 winner): out = post(A @ Wt^T + bias), Wt pre-transposed.
// Tile 128x128, BK=32, 4 waves.
// ---------------------------------------------------------------------------
template <int ACT, int BN_, int OUTB>
__global__ __launch_bounds__(256) void mfma_gemm(
    const __hip_bfloat16* __restrict__ A, const __hip_bfloat16* __restrict__ Wt,
    const float* __restrict__ bias, const float* __restrict__ gamma,
    const float* __restrict__ beta, void* __restrict__ outp, int K, int Ncols) {
    __shared__ __bf16 As[128][40];
    __shared__ __bf16 Bs[128][40];
    const int tid = threadIdx.x;
    const int w = tid >> 6, l = tid & 63;
    const int wm = w >> 1, wn = w & 1;
    const long row0 = (long)blockIdx.x * 128;
    const int col0 = blockIdx.y * 128;
    const int sr = tid >> 1, sh = tid & 1;
    const int fr = l & 15, kg = (l >> 4) * 8;
    f32x4 acc[4][4] = {};
    const __hip_bfloat16* __restrict__ ap = A + (row0 + sr) * (long)K + sh * 16;
    const __hip_bfloat16* __restrict__ bp =
        Wt + (long)(col0 + sr) * K + sh * 16;
    for (int k0 = 0; k0 < K; k0 += 32) {
        const uint4 av0 = *reinterpret_cast<const uint4*>(ap + k0);
        const uint4 av1 = *reinterpret_cast<const uint4*>(ap + k0 + 8);
        const uint4 bv0 = *reinterpret_cast<const uint4*>(bp + k0);
        const uint4 bv1 = *reinterpret_cast<const uint4*>(bp + k0 + 8);
        *reinterpret_cast<uint4*>(&As[sr][sh * 16]) = av0;
        *reinterpret_cast<uint4*>(&As[sr][sh * 16 + 8]) = av1;
        *reinterpret_cast<uint4*>(&Bs[sr][sh * 16]) = bv0;
        *reinterpret_cast<uint4*>(&Bs[sr][sh * 16 + 8]) = bv1;
        __syncthreads();
        bf16x8 af[4], bfv[4];
#pragma unroll
        for (int mt = 0; mt < 4; ++mt)
            af[mt] =
                *reinterpret_cast<const bf16x8*>(&As[wm * 64 + mt * 16 + fr][kg]);
#pragma unroll
        for (int nt = 0; nt < 4; ++nt)
            bfv[nt] =
                *reinterpret_cast<const bf16x8*>(&Bs[wn * 64 + nt * 16 + fr][kg]);
#pragma unroll
        for (int mt = 0; mt < 4; ++mt)
#pragma unroll
            for (int nt = 0; nt < 4; ++nt)
                acc[mt][nt] = __builtin_amdgcn_mfma_f32_16x16x32_bf16(
                    af[mt], bfv[nt], acc[mt][nt], 0, 0, 0);
        __syncthreads();
    }
    const int rg = (l >> 4) * 4;
#pragma unroll
    for (int nt = 0; nt < 4; ++nt) {
        const int col = col0 + wn * 64 + nt * 16 + fr;
        const float bb = bias[col];
        const float gs = BN_ ? gamma[col] * RS : 0.0f;
        const float bt = BN_ ? beta[col] : 0.0f;
#pragma unroll
        for (int mt = 0; mt < 4; ++mt) {
#pragma unroll
            for (int r = 0; r < 4; ++r) {
                const long row = row0 + wm * 64 + mt * 16 + rg + r;
                float v = acc[mt][nt][r] + bb;
                if (ACT) v = eluf(v);
                if (BN_) v = v * gs + bt;
                if (OUTB)
                    reinterpret_cast<__hip_bfloat16*>(outp)[row * Ncols + col] =
                        __float2bfloat16(v);
                else
                    reinterpret_cast<float*>(outp)[row * Ncols + col] = v;
            }
        }
    }
}

// ---------------------------------------------------------------------------
// Setup: pts_local (f32 store) + Xc (bf16 store). 16 pts/block, grid 2048.
// ---------------------------------------------------------------------------
__global__ __launch_bounds__(256) void setup_kernel(
    const float* __restrict__ rep_pts, const float* __restrict__ pts,
    const int* __restrict__ pts_idx, const float* __restrict__ xt_cW,
    const float* __restrict__ xt_cb, float* __restrict__ pts_local,
    __hip_bfloat16* __restrict__ Xc) {
    __shared__ float cwT[48][256];
    __shared__ float pl2[16][48];
    __shared__ float cb_s[256];
    const int tid = threadIdx.x;
    const long gp0 = (long)blockIdx.x * 16;
#pragma unroll
    for (int i = 0; i < 48; ++i) {
        const int e = i * 256 + tid;
        const int o = e / 48, r = e - o * 48;
        cwT[r][o] = xt_cW[e];
    }
    cb_s[tid] = xt_cb[tid];
    {
        const int pt = tid >> 4, k = tid & 15;
        const long gp = gp0 + pt;
        const int n = (int)(gp >> 11);
        const int idx = pts_idx[gp * 32 + 2 * k];
        const float* ps = pts + ((long)n * 8192 + idx) * 3;
        const float* rs = rep_pts + gp * 3;
        float* plo = pts_local + gp * 48 + k * 3;
#pragma unroll
        for (int d = 0; d < 3; ++d) {
            const float v = ps[d] - rs[d];
            pl2[pt][d * 16 + k] = v;
            plo[d] = v;
        }
    }
    __syncthreads();
    const int o = tid;
    for (int pt = 0; pt < 16; ++pt) {
        float acc = cb_s[o];
#pragma unroll
        for (int i = 0; i < 48; ++i) acc = fmaf(pl2[pt][i], cwT[i][o], acc);
        Xc[(gp0 + pt) * 256 + o] = __float2bfloat16(eluf(acc));
    }
}

// ---------------------------------------------------------------------------
// Final per-point stage v8: 8 points per wave, software-pipelined (prefetch
// next point's gather/X/pl while computing current). 4 waves/block, grid 1024.
// XCD swizzle: XCD x gets contiguous 128 blocks = 4096 points = 2 batches.
// All LDS wave-private (in-wave DS ordering => no barriers).
// NOTE: no 2nd __launch_bounds__ arg (R4: (256,4) clamp -> 64 VGPR spill).
// ---------------------------------------------------------------------------
__global__ __launch_bounds__(256) void final_stage_kernel(
    const __hip_bfloat16* __restrict__ X2B,  // [32768][256] bf16
    const float* __restrict__ pts_local,     // [32768][48] (k*3+d)
    const int* __restrict__ pts_idx,
    const __hip_bfloat16* __restrict__ fts_lB,  // [131072][64] bf16
    const float* __restrict__ d1_W, const float* __restrict__ d1_b,
    const float* __restrict__ d1_g, const float* __restrict__ d1_bt,
    const __hip_bfloat16* __restrict__ d2pWt,  // [32 c][32 q] bf16
    const float* __restrict__ d2_b, const float* __restrict__ d2_g,
    const float* __restrict__ d2_bt, const float* __restrict__ dw_W,
    const float* __restrict__ dw_b,
    __hip_bfloat16* __restrict__ dw_out)  // [32768][192] bf16
{
    __shared__ __bf16 fcat[4][96][24];  // wave-private

    const int tid = threadIdx.x;
    const int w = tid >> 6, l = tid & 63;
    const int obid = blockIdx.x;
    const int bid = (obid & 7) * 128 + (obid >> 3);  // bijective, 1024%8==0
    const int base = __builtin_amdgcn_readfirstlane(bid * 32 + w * 8);
    const int n = base >> 11;  // all 8 pts in same batch (base % 8 == 0)
    const int fr = l & 15;
    const int kg = (l >> 4) * 8;
    const int kk = kg & 15;
    const unsigned msk = (l < 32) ? 0xFFFFFFFFu : 0u;
    const int rg4 = (l >> 4) * 4;
    const int colg = (l < 32) ? (32 + l) : (l - 32);
    const __hip_bfloat16* __restrict__ fbase =
        fts_lB + (long)n * 8192 * 64 + colg;

// issue loads for point (G) into fg/ax/pl registers
#define ISSUE(G, FG, AX, P0, P1, P2)                                          \
    {                                                                         \
        const int* __restrict__ ip_ = pts_idx + (long)(G) * 32;               \
        _Pragma("unroll") for (int j = 0; j < 16; ++j) FG[j] =                \
            *reinterpret_cast<const unsigned short*>(                         \
                &fbase[(long)ip_[2 * j] * 64]);                               \
        AX = *reinterpret_cast<const u32x4*>(X2B + (long)(G) * 256 +          \
                                             fr * 16 + kk);                   \
        const float* __restrict__ pp_ = pts_local + (long)(G) * 48 + fr * 3;  \
        P0 = pp_[0];                                                          \
        P1 = pp_[1];                                                          \
        P2 = pp_[2];                                                          \
    }

    unsigned fgA[16];
    u32x4 axA;
    float plA0, plA1, plA2;
    ISSUE(base, fgA, axA, plA0, plA1, plA2);

#pragma unroll
    for (int it = 0; it < 8; ++it) {
        const int gp = base + it;
        unsigned fgB[16];
        u32x4 axB;
        float plB0 = 0, plB1 = 0, plB2 = 0;
        if (it < 7) ISSUE(gp + 1, fgB, axB, plB0, plB1, plB2);

        // ---- l0 row-owner A-frag: lane = row fr, k-cols kg..kg+7 ----
        bf16x8 a_l0;
#pragma unroll
        for (int jj = 0; jj < 8; ++jj) {
            const int q = kg + jj;
            float a = d1_b[q];
            a = fmaf(plA0, d1_W[q], a);
            a = fmaf(plA1, d1_W[32 + q], a);
            a = fmaf(plA2, d1_W[64 + q], a);
            a = eluf(a);
            a = a * (d1_g[q] * RS) + d1_bt[q];
            a_l0[jj] = (__bf16)a;
        }

        // ---- lifted = l0 @ d2_W via 2 MFMA (K=32 exact) -> fcat cols 0..31 --
        {
            const bf16x8 b0 =
                *reinterpret_cast<const bf16x8*>(d2pWt + (0 + fr) * 32 + kg);
            const bf16x8 b1 =
                *reinterpret_cast<const bf16x8*>(d2pWt + (16 + fr) * 32 + kg);
            f32x4 lif0 = {}, lif1 = {};
            lif0 =
                __builtin_amdgcn_mfma_f32_16x16x32_bf16(a_l0, b0, lif0, 0, 0, 0);
            lif1 =
                __builtin_amdgcn_mfma_f32_16x16x32_bf16(a_l0, b1, lif1, 0, 0, 0);
#pragma unroll
            for (int f = 0; f < 2; ++f) {
                const int c = f * 16 + fr;
                const float bb = d2_b[c], gs = d2_g[c] * RS, bt = d2_bt[c];
                const f32x4 dd = f ? lif1 : lif0;
                unsigned short pk[4];
#pragma unroll
                for (int r = 0; r < 4; ++r) {
                    float v = dd[r] + bb;
                    v = eluf(v) * gs + bt;
                    const __bf16 h = (__bf16)v;
                    pk[r] = *reinterpret_cast<const unsigned short*>(&h);
                }
                *reinterpret_cast<uint2*>(&fcat[w][c][rg4]) =
                    make_uint2((unsigned)pk[0] | ((unsigned)pk[1] << 16),
                               (unsigned)pk[2] | ((unsigned)pk[3] << 16));
            }
        }

        // ---- fgA (bf16 bits) -> fcat[32+colg][0..15] (2 x ds_write_b128) ---
        {
            const uint4 lo =
                make_uint4(fgA[0] | (fgA[1] << 16), fgA[2] | (fgA[3] << 16),
                           fgA[4] | (fgA[5] << 16), fgA[6] | (fgA[7] << 16));
            const uint4 hi =
                make_uint4(fgA[8] | (fgA[9] << 16), fgA[10] | (fgA[11] << 16),
                           fgA[12] | (fgA[13] << 16), fgA[14] | (fgA[15] << 16));
            *reinterpret_cast<uint4*>(&fcat[w][32 + colg][0]) = lo;
            *reinterpret_cast<uint4*>(&fcat[w][32 + colg][8]) = hi;
        }

        // ---- A-frag: X row fr (zero k>=16 half via mask) ----
        u32x4 axu = axA & msk;
        const bf16x8 ax = *reinterpret_cast<const bf16x8*>(&axu);

        // ---- fts_X: 6 B-frags from fcat + 6 MFMA ----
        f32x4 acc[6];
#pragma unroll
        for (int f = 0; f < 6; ++f) acc[f] = (f32x4){};
#pragma unroll
        for (int f = 0; f < 6; ++f) {
            u32x4 bu =
                *reinterpret_cast<const u32x4*>(&fcat[w][f * 16 + fr][kk]);
            bu &= msk;  // zero k>=16 (also kills uninit-LDS NaN)
            const bf16x8 bf = *reinterpret_cast<const bf16x8*>(&bu);
            acc[f] =
                __builtin_amdgcn_mfma_f32_16x16x32_bf16(ax, bf, acc[f], 0, 0, 0);
        }

        // ---- dw: partials rows rg4..rg4+3, butterfly, store (lanes<16) ----
        float dwv[6][2];
#pragma unroll
        for (int f = 0; f < 6; ++f) {
            const int c = f * 16 + fr;
            const float4 w0 =
                *reinterpret_cast<const float4*>(dw_W + c * 32 + rg4);
            const float4 w1 =
                *reinterpret_cast<const float4*>(dw_W + c * 32 + 16 + rg4);
            float p0 = acc[f][0] * w0.x;
            p0 = fmaf(acc[f][1], w0.y, p0);
            p0 = fmaf(acc[f][2], w0.z, p0);
            p0 = fmaf(acc[f][3], w0.w, p0);
            float p1 = acc[f][0] * w1.x;
            p1 = fmaf(acc[f][1], w1.y, p1);
            p1 = fmaf(acc[f][2], w1.z, p1);
            p1 = fmaf(acc[f][3], w1.w, p1);
            p0 += __shfl_xor(p0, 16);
            p0 += __shfl_xor(p0, 32);
            p1 += __shfl_xor(p1, 16);
            p1 += __shfl_xor(p1, 32);
            dwv[f][0] = p0;
            dwv[f][1] = p1;
        }
        if (l < 16) {
#pragma unroll
            for (int f = 0; f < 6; ++f) {
                const int c = f * 16 + l;
                __hip_bfloat162 pk;
                pk.x = __float2bfloat16(dwv[f][0] + dw_b[2 * c + 0]);
                pk.y = __float2bfloat16(dwv[f][1] + dw_b[2 * c + 1]);
                *reinterpret_cast<__hip_bfloat162*>(dw_out + (long)gp * 192 +
                                                    2 * c) = pk;
            }
        }

        // ---- rotate prefetch ----
        if (it < 7) {
#pragma unroll
            for (int j = 0; j < 16; ++j) fgA[j] = fgB[j];
            axA = axB;
            plA0 = plB0;
            plA1 = plB1;
            plA2 = plB2;
        }
    }
#undef ISSUE
}

extern "C" void kernel_launch(void* const* d_in, const int* in_sizes, int n_in,
                              void* d_out, int out_size, void* d_ws,
                              size_t ws_size, hipStream_t stream) {
    const float* rep_pts = (const float*)d_in[0];
    const float* pts = (const float*)d_in[1];
    const float* fts = (const float*)d_in[2];
    const int* pts_idx = (const int*)d_in[3];
    const float* dense_W = (const float*)d_in[4];
    const float* dense_b = (const float*)d_in[5];
    const float* dense_g = (const float*)d_in[6];
    const float* dense_bt = (const float*)d_in[7];
    const float* d1_W = (const float*)d_in[8];
    const float* d1_b = (const float*)d_in[9];
    const float* d1_g = (const float*)d_in[10];
    const float* d1_bt = (const float*)d_in[11];
    const float* d2_W = (const float*)d_in[12];
    const float* d2_b = (const float*)d_in[13];
    const float* d2_g = (const float*)d_in[14];
    const float* d2_bt = (const float*)d_in[15];
    const float* xt_cW = (const float*)d_in[16];
    const float* xt_cb = (const float*)d_in[17];
    const float* xt_d1W = (const float*)d_in[18];
    const float* xt_d1b = (const float*)d_in[19];
    const float* xt_d2W = (const float*)d_in[20];
    const float* xt_d2b = (const float*)d_in[21];
    const float* dw_W = (const float*)d_in[22];
    const float* dw_b = (const float*)d_in[23];
    const float* pw_W = (const float*)d_in[24];
    const float* pw_b = (const float*)d_in[25];
    const float* sep_g = (const float*)d_in[26];
    const float* sep_bt = (const float*)d_in[27];

    float* ws = (float*)d_ws;
    __hip_bfloat16* fts_lB = (__hip_bfloat16*)ws;              // 8388608 bf16
    __hip_bfloat16* X2Bb = (__hip_bfloat16*)(ws + 8388608);    // 8388608 bf16
    __hip_bfloat16* XcB = (__hip_bfloat16*)(ws + 16777216);    // 8388608 bf16
    __hip_bfloat16* dwB = (__hip_bfloat16*)(ws + 16777216);    // overlays XcB
    __hip_bfloat16* X1B = (__hip_bfloat16*)(ws + 20971520);    // 8388608 bf16
    float* pl = ws + 25165824;                                 // 1572864 f32
    __hip_bfloat16* d1Wt = (__hip_bfloat16*)(ws + 26738688);   // 65536 bf16
    __hip_bfloat16* d2Wt = (__hip_bfloat16*)(ws + 26771456);   // 65536 bf16
    __hip_bfloat16* pwWt = (__hip_bfloat16*)(ws + 26804224);   // 24576 bf16
    __hip_bfloat16* d2pWt = (__hip_bfloat16*)(ws + 26816512);  // 1024 bf16

    // 0) weight convert+transpose to bf16
    convert_weights<<<256, 256, 0, stream>>>(xt_d1W, xt_d2W, pw_W, d2_W, d1Wt,
                                             d2Wt, pwWt, d2pWt);

    // 1) fts_l = bn(elu(fts @ dense_W + b))  f32 GEMM -> bf16 out
    gemm_bias_act<1, 1, 1><<<dim3(2048, 1), 256, 0, stream>>>(
        fts, dense_W, dense_b, dense_g, dense_bt, fts_lB, 64, 64);

    // 2) pts_local + Xc (bf16)
    setup_kernel<<<2048, 256, 0, stream>>>(rep_pts, pts, pts_idx, xt_cW, xt_cb,
                                           pl, XcB);

    // 3) X1 = elu(Xc @ xt_d1W + b)  bf16 MFMA -> bf16
    mfma_gemm<1, 0, 1><<<dim3(256, 2), 256, 0, stream>>>(
        XcB, d1Wt, xt_d1b, nullptr, nullptr, X1B, 256, 256);

    // 4) X2 = X1 @ xt_d2W + b  bf16 MFMA -> bf16
    mfma_gemm<0, 0, 1><<<dim3(256, 2), 256, 0, stream>>>(
        X1B, d2Wt, xt_d2b, nullptr, nullptr, X2Bb, 256, 256);

    // 5) lifted/gather/fts_X/dw -> dwB (bf16), 8 pts/wave pipelined
    final_stage_kernel<<<1024, 256, 0, stream>>>(
        X2Bb, pl, pts_idx, fts_lB, d1_W, d1_b, d1_g, d1_bt, d2pWt, d2_b, d2_g,
        d2_bt, dw_W, dw_b, dwB);

    // 6) out = bn(elu(dw @ pw_W + pw_b))  bf16 MFMA -> f32
    mfma_gemm<1, 1, 0><<<dim3(256, 1), 256, 0, stream>>>(
        dwB, pwWt, pw_b, sep_g, sep_bt, d_out, 192, 128);
}